// Round 4
// baseline (719.409 us; speedup 1.0000x reference)
//
#include <hip/hip_runtime.h>
#include <math.h>

#define B      64
#define T      2048
#define RNN_H  1024
#define EMB    512
#define ATT    128
#define NF     32
#define KW     31
#define PADW   15

#define TT  64               // t-tile per energy block
#define CW  (TT + KW - 1)    // 94 staged cum columns

__device__ __forceinline__ float fast_tanh(float x) {
    x = fminf(fmaxf(x, -15.f), 15.f);
    float e = __expf(2.f * x);
    return (e - 1.f) / (e + 1.f);
}

// ---------------- K1: after_query[b][a] = dot(hidden[b,:], Wdec[a,:]) --------
__global__ __launch_bounds__(256) void k_query(const float* __restrict__ hidden,
                                               const float* __restrict__ Wdec,
                                               float* __restrict__ aq) {
    int gw   = (blockIdx.x * blockDim.x + threadIdx.x) >> 6;  // wave id = b*ATT + a
    int lane = threadIdx.x & 63;
    int b = gw >> 7, a = gw & (ATT - 1);
    const float4* h = (const float4*)(hidden + b * RNN_H);
    const float4* w = (const float4*)(Wdec   + a * RNN_H);
    float acc = 0.f;
#pragma unroll
    for (int i = 0; i < RNN_H / 4 / 64; ++i) {         // 4 iters
        float4 hv = h[lane + i * 64];
        float4 wv = w[lane + i * 64];
        acc += hv.x * wv.x + hv.y * wv.y + hv.z * wv.z + hv.w * wv.w;
    }
#pragma unroll
    for (int off = 32; off; off >>= 1) acc += __shfl_down(acc, off);
    if (lane == 0) aq[gw] = acc;
}

// ---------------- K2: fused conv1d -> loc-linear -> tanh -> energy ----------
// Also zeroes its 16-float slice of ctx (stream-ordered before K3).
// Hot phase restructured: wloc hoisted to regs (t-invariant), loop nest
// c-outer with 16 t-accumulators in regs, loc read as uniform ds_read_b128
// broadcasts, mem_after prefetched before the tanh epilogue.
__global__ __launch_bounds__(256) void k_energy(
    const float* __restrict__ cum,       // [B][2][T]
    const float* __restrict__ mem_after, // [B][T][ATT]
    const int*   __restrict__ mask,      // [B][T]
    const float* __restrict__ Wconv,     // [NF][2][KW]
    const float* __restrict__ Wloc,      // [ATT][NF]
    const float* __restrict__ Wenergy,   // [ATT]
    const float* __restrict__ aq,        // [B][ATT]
    float* __restrict__ en,              // [B][T] energies (ws scratch)
    float* __restrict__ ctx)             // [B][EMB] (zero-init here)
{
    __shared__ float cum_s[2][CW];
    __shared__ float wconv_s[NF * 2 * KW];  // [c][ch][k]
    __shared__ float wloc_s[NF * ATT];      // transposed: [c][a]
    __shared__ float wen_s[ATT];
    __shared__ float aq_s[ATT];
    __shared__ float loc_s[NF * TT];        // [c][t]

    int tid = threadIdx.x;
    int b   = blockIdx.x >> 5;   // T/TT == 32 tiles per batch row
    int tc  = blockIdx.x & 31;
    int t0  = tc * TT;

    if (tid < 16) ctx[b * EMB + tc * 16 + tid] = 0.f;   // 32 tiles x 16 = EMB

    for (int i = tid; i < NF * 2 * KW; i += 256) wconv_s[i] = Wconv[i];
    for (int i = tid; i < NF * ATT; i += 256) {
        int c = i >> 7, a = i & (ATT - 1);
        wloc_s[i] = Wloc[a * NF + c];
    }
    if (tid < ATT) { wen_s[tid] = Wenergy[tid]; aq_s[tid] = aq[b * ATT + tid]; }
    for (int i = tid; i < 2 * CW; i += 256) {
        int ch = i / CW, j = i - ch * CW;
        int t  = t0 + j - PADW;
        cum_s[ch][j] = (t >= 0 && t < T) ? cum[(b * 2 + ch) * T + t] : 0.f;
    }
    __syncthreads();

    // conv: loc[c][tl] = sum_{ch,k} cum_s[ch][tl+k] * Wconv[c][ch][k]
    for (int i = tid; i < NF * TT; i += 256) {
        int c = i >> 6, tl = i & 63;
        const float* wc = &wconv_s[c * 2 * KW];
        float acc = 0.f;
#pragma unroll
        for (int k = 0; k < KW; ++k) {
            acc += cum_s[0][tl + k] * wc[k];
            acc += cum_s[1][tl + k] * wc[KW + k];
        }
        loc_s[i] = acc;
    }
    __syncthreads();

    int wv = tid >> 6, lane = tid & 63;

    // t-invariant operands hoisted to registers (was re-read from LDS per t)
    float2 wl[NF];
#pragma unroll
    for (int c = 0; c < NF; ++c) wl[c] = ((const float2*)wloc_s)[c * (ATT / 2) + lane];
    float2 aq2 = ((const float2*)aq_s)[lane];
    float2 we2 = ((const float2*)wen_s)[lane];

    // accumulate ax/ay for this wave's 16 t's; c outer, loc via b128 broadcast
    float ax[16], ay[16];
#pragma unroll
    for (int j = 0; j < 16; ++j) { ax[j] = aq2.x; ay[j] = aq2.y; }

    const float4* loc4 = (const float4*)loc_s;  // [c][TT/4]
#pragma unroll
    for (int c = 0; c < NF; ++c) {
        float2 w = wl[c];
#pragma unroll
        for (int q = 0; q < 4; ++q) {
            float4 lv = loc4[c * (TT / 4) + wv * 4 + q];  // uniform -> broadcast
            ax[q * 4 + 0] += lv.x * w.x; ay[q * 4 + 0] += lv.x * w.y;
            ax[q * 4 + 1] += lv.y * w.x; ay[q * 4 + 1] += lv.y * w.y;
            ax[q * 4 + 2] += lv.z * w.x; ay[q * 4 + 2] += lv.z * w.y;
            ax[q * 4 + 3] += lv.w * w.x; ay[q * 4 + 3] += lv.w * w.y;
        }
    }

    // prefetch all 16 mem_after rows (pipelined global loads), then epilogue
    float2 ma[16];
#pragma unroll
    for (int j = 0; j < 16; ++j) {
        int t = t0 + wv * 16 + j;
        ma[j] = ((const float2*)(mem_after + (size_t)(b * T + t) * ATT))[lane];
    }

#pragma unroll
    for (int j = 0; j < 16; ++j) {
        int t = t0 + wv * 16 + j;
        float e0 = fast_tanh(ax[j] + ma[j].x);
        float e1 = fast_tanh(ay[j] + ma[j].y);
        float s  = we2.x * e0 + we2.y * e1;
#pragma unroll
        for (int off = 32; off; off >>= 1) s += __shfl_down(s, off);
        if (lane == 0)
            en[b * T + t] = mask[b * T + t] ? -INFINITY : s;
    }
}

// ---------------- K3: fused softmax + weights write + context ---------------
__global__ __launch_bounds__(128) void k_softmax_ctx(
    const float* __restrict__ en,      // [B][T] energies (ws)
    const float* __restrict__ memory,  // [B][T][EMB]
    float* __restrict__ wts,           // [B][T] softmax weights (output)
    float* __restrict__ ctx)           // [B][EMB] (pre-zeroed, atomic)
{
    __shared__ float redm[2], reds[2];
    __shared__ float ws_[64];
    int b = blockIdx.x >> 5, tc = blockIdx.x & 31;
    int t0 = tc * 64, tid = threadIdx.x;

    const float* row = en + b * T;
    float e[16];
    float m = -INFINITY;
#pragma unroll
    for (int j = 0; j < 16; ++j) { e[j] = row[tid + j * 128]; m = fmaxf(m, e[j]); }
#pragma unroll
    for (int off = 32; off; off >>= 1) m = fmaxf(m, __shfl_xor(m, off));
    if ((tid & 63) == 0) redm[tid >> 6] = m;
    __syncthreads();
    m = fmaxf(redm[0], redm[1]);

    float s = 0.f;
#pragma unroll
    for (int j = 0; j < 16; ++j) s += __expf(e[j] - m);
#pragma unroll
    for (int off = 32; off; off >>= 1) s += __shfl_xor(s, off);
    if ((tid & 63) == 0) reds[tid >> 6] = s;
    __syncthreads();
    float inv = 1.f / (reds[0] + reds[1]);

    // weights for this block's window (reload from L2 — avoids runtime-indexed
    // register array -> scratch, rule #20)
    if (tid < 64) {
        float w = __expf(row[t0 + tid] - m) * inv;
        wts[b * T + t0 + tid] = w;
        ws_[tid] = w;
    }
    __syncthreads();

    const float4* mem4 = (const float4*)memory + (size_t)(b * T + t0) * (EMB / 4);
    float4 acc = make_float4(0.f, 0.f, 0.f, 0.f);
#pragma unroll 8
    for (int t = 0; t < 64; ++t) {
        float  wt = ws_[t];
        float4 mv = mem4[(size_t)t * (EMB / 4) + tid];
        acc.x += wt * mv.x; acc.y += wt * mv.y; acc.z += wt * mv.z; acc.w += wt * mv.w;
    }
    float* dst = ctx + b * EMB + tid * 4;
    atomicAdd(dst + 0, acc.x);
    atomicAdd(dst + 1, acc.y);
    atomicAdd(dst + 2, acc.z);
    atomicAdd(dst + 3, acc.w);
}

extern "C" void kernel_launch(void* const* d_in, const int* in_sizes, int n_in,
                              void* d_out, int out_size, void* d_ws, size_t ws_size,
                              hipStream_t stream) {
    const float* hidden    = (const float*)d_in[0];  // [B, RNN_H]
    const float* memory    = (const float*)d_in[1];  // [B, T, EMB]
    const float* mem_after = (const float*)d_in[2];  // [B, T, ATT]
    const float* cum       = (const float*)d_in[3];  // [B, 2, T]
    const int*   mask      = (const int*)  d_in[4];  // [B, T]
    const float* Wdec      = (const float*)d_in[5];  // [ATT, RNN_H]
    const float* Wconv     = (const float*)d_in[6];  // [NF, 2, KW]
    const float* Wloc      = (const float*)d_in[7];  // [ATT, NF]
    const float* Wenergy   = (const float*)d_in[8];  // [1, ATT]

    float* ctx = (float*)d_out;            // [B, EMB]
    float* wts = (float*)d_out + B * EMB;  // [B, T]
    float* aq  = (float*)d_ws;             // [B, ATT]
    float* en  = (float*)d_ws + B * ATT;   // [B, T] energies scratch

    // K1: one wave per (b,a) output
    k_query<<<(B * ATT) / 4, 256, 0, stream>>>(hidden, Wdec, aq);

    // K2: grid = B * (T/TT) = 2048 blocks; also zeroes ctx
    k_energy<<<B * (T / TT), 256, 0, stream>>>(cum, mem_after, mask, Wconv, Wloc,
                                               Wenergy, aq, en, ctx);

    // K3: fused softmax + context, grid = B * (T/64) = 2048 blocks
    k_softmax_ctx<<<B * (T / 64), 128, 0, stream>>>(en, memory, wts, ctx);
}